// Round 7
// baseline (546.809 us; speedup 1.0000x reference)
//
#include <hip/hip_runtime.h>
#include <math.h>

#define NROW 16384   // B*N rows
#define NCOL 4096
#define CDIM 256
#define DKDIM 64
#define SCALE 0.125f // DK^-0.5

typedef float v4f __attribute__((ext_vector_type(4)));  // for nontemporal stores

// ---------------- Kernel 1: fused Q/K projection ----------------
// Output layout (both Q and K): T4[(b*16 + dg)*4096 + n] = proj[n][4*dg .. 4*dg+3]
__global__ __launch_bounds__(512, 2) void qk_proj(
    const float* __restrict__ x, const float* __restrict__ Wq,
    const float* __restrict__ Wk, float* __restrict__ Qt,
    float* __restrict__ Kt) {
  __shared__ float4 xs4[64][65];  // row stride 65 f4-units -> bank-group spread
  const int t = threadIdx.x;
  const int rb = blockIdx.x;      // 256 blocks of 64 rows
  {
    const float4* xg = (const float4*)(x + (size_t)rb * 64 * CDIM);
    #pragma unroll
    for (int i = 0; i < 8; ++i) {
      int idx = i * 512 + t;      // 0..4095
      xs4[idx >> 6][idx & 63] = xg[idx];
    }
  }
  __syncthreads();

  const int lane = t & 63;
  const int wu = __builtin_amdgcn_readfirstlane(t >> 6);  // wave id, uniform
  const int proj = wu >> 2;
  const int chunk = wu & 3;       // d-chunk: d = chunk*16 .. +15
  const float* __restrict__ Wp = proj ? Wk : Wq;

  float acc[16];
  #pragma unroll
  for (int j = 0; j < 16; ++j) acc[j] = 0.f;

  #pragma unroll 4
  for (int cs = 0; cs < 64; ++cs) {        // 4 c's per step
    float4 xv = xs4[lane][cs];
    const float xc[4] = {xv.x, xv.y, xv.z, xv.w};
    #pragma unroll
    for (int i = 0; i < 4; ++i) {
      const float4* __restrict__ w4 =
          (const float4*)(Wp + (size_t)(cs * 4 + i) * DKDIM + chunk * 16);
      float4 wa = w4[0], wb = w4[1], wc = w4[2], wd = w4[3];
      float xi = xc[i];
      acc[0]  = fmaf(xi, wa.x, acc[0]);  acc[1]  = fmaf(xi, wa.y, acc[1]);
      acc[2]  = fmaf(xi, wa.z, acc[2]);  acc[3]  = fmaf(xi, wa.w, acc[3]);
      acc[4]  = fmaf(xi, wb.x, acc[4]);  acc[5]  = fmaf(xi, wb.y, acc[5]);
      acc[6]  = fmaf(xi, wb.z, acc[6]);  acc[7]  = fmaf(xi, wb.w, acc[7]);
      acc[8]  = fmaf(xi, wc.x, acc[8]);  acc[9]  = fmaf(xi, wc.y, acc[9]);
      acc[10] = fmaf(xi, wc.z, acc[10]); acc[11] = fmaf(xi, wc.w, acc[11]);
      acc[12] = fmaf(xi, wd.x, acc[12]); acc[13] = fmaf(xi, wd.y, acc[13]);
      acc[14] = fmaf(xi, wd.z, acc[14]); acc[15] = fmaf(xi, wd.w, acc[15]);
    }
  }

  const int gr = rb * 64 + lane;  // global row
  const int b = gr >> 12;
  const int n = gr & 4095;
  float4* __restrict__ Out4 = (float4*)(proj ? Kt : Qt);
  #pragma unroll
  for (int i = 0; i < 4; ++i) {
    int dg = chunk * 4 + i;
    float4 o = {acc[4 * i], acc[4 * i + 1], acc[4 * i + 2], acc[4 * i + 3]};
    Out4[(size_t)(b * 16 + dg) * 4096 + n] = o;  // lane-consecutive: coalesced
  }
}

// ---------------- Kernel 2: fused S = Q K^T + per-row top-8 ----------------
// Block = 128 rows x 512 cols; 4 waves, each a 128-col stripe; lane covers
// rows {lane, lane+64} -> each wave-uniform K s_load feeds 2x the FMAs
// (256 busy cyc per 64-SGPR segment vs 128 before: doubles per-wave duty).
// Grid 1024 = exactly 4 blocks/CU (LDS 33.8 KB) = 16 waves/CU, one pass.
// XCD swizzle: 4 (b,chunk) combos per XCD-slot -> K 512 KB/XCD, L2-hot.
__global__ __launch_bounds__(256, 4) void s_topk(
    const float* __restrict__ Qt, const float* __restrict__ Kt,
    float* __restrict__ out, float* __restrict__ wsv, int* __restrict__ wsi) {
  __shared__ float smem[8448];            // 33.8 KB: q-stage / merge union
  float4* qs = (float4*)smem;             // [g*128 + row], 2048 float4 = 32 KB
  float (*cv)[33] = (float(*)[33])smem;   // merge view (aliases qs), 128 rows
  int   (*ci)[33] = (int(*)[33])(smem + 128 * 33);

  const int t = threadIdx.x;
  const int f = blockIdx.x;        // 0..1023
  const int slot = f & 7;          // XCD-slot (dispatch heuristic: f%8 ~ XCD)
  const int i5 = f >> 3;           // 0..127
  const int cl = i5 >> 5;          // 0..3
  const int rbL = i5 & 31;         // rowblock-of-128 within batch
  const int combo = slot * 4 + cl; // 0..31
  const int b = combo >> 3;        // batch
  const int chunk = combo & 7;     // col-chunk of 512
  const int lane = t & 63;
  const int wu = __builtin_amdgcn_readfirstlane(t >> 6);  // wave id
  const int n0 = rbL * 128;        // row base within batch

  // 1) stage Q rows into LDS (coalesced global, stride-16B LDS writes)
  const float4* __restrict__ Qt4 = (const float4*)Qt;
  #pragma unroll
  for (int i = 0; i < 8; ++i) {
    int idx = i * 256 + t;         // 0..2047
    int g = idx >> 7, row = idx & 127;
    qs[g * 128 + row] = Qt4[(size_t)(b * 16 + g) * 4096 + n0 + row];
  }
  __syncthreads();

  // 2) zero-fill my 128x512 output region (fire-and-forget, nontemporal;
  //    drains in the background during the cg loop)
  {
    v4f z = {0.f, 0.f, 0.f, 0.f};
    v4f* o4 = (v4f*)out + (size_t)(b * 4096 + n0) * 1024 + chunk * 128;
    #pragma unroll 8
    for (int i = 0; i < 64; ++i) {
      int g = i * 256 + t;         // 0..16383: 128 rows x 128 f4
      __builtin_nontemporal_store(z, &o4[(size_t)(g >> 7) * 1024 + (g & 127)]);
    }
  }

  const float4* __restrict__ Kt4 = (const float4*)Kt;
  const int stripe = chunk * 512 + wu * 128;  // my wave's 128-col stripe

  float tv0[8], tv1[8]; int ti0[8], ti1[8];
  float tmin0, tmin1; int tmpos0, tmpos1;

  auto compute8 = [&](int cb, float* a0, float* a1) {
    #pragma unroll
    for (int j = 0; j < 8; ++j) { a0[j] = 0.f; a1[j] = 0.f; }
    #pragma unroll 2
    for (int g = 0; g < 16; ++g) {
      float4 qa = qs[g * 128 + lane];                     // ds_read_b128
      float4 qb = qs[g * 128 + 64 + lane];                // ds_read_b128
      const float4* __restrict__ kg =
          Kt4 + (size_t)(b * 16 + g) * 4096 + cb;         // uniform -> s_load
      #pragma unroll
      for (int j = 0; j < 8; ++j) {
        float4 kf = kg[j];
        a0[j] = fmaf(qa.x, kf.x, a0[j]);
        a0[j] = fmaf(qa.y, kf.y, a0[j]);
        a0[j] = fmaf(qa.z, kf.z, a0[j]);
        a0[j] = fmaf(qa.w, kf.w, a0[j]);
        a1[j] = fmaf(qb.x, kf.x, a1[j]);
        a1[j] = fmaf(qb.y, kf.y, a1[j]);
        a1[j] = fmaf(qb.z, kf.z, a1[j]);
        a1[j] = fmaf(qb.w, kf.w, a1[j]);
      }
    }
  };

  // per-row-half top-8 insert (seed-free path), reused for both halves
  auto update8 = [&](int cb, float* acc, float* tv, int* ti,
                     float& tmin, int& tmpos) {
    float bv = acc[0]; int bj = 0;
    #pragma unroll
    for (int j = 1; j < 8; ++j)
      if (acc[j] > bv) { bv = acc[j]; bj = j; }
    #pragma unroll
    for (int pass = 0; pass < 2; ++pass) {
      if (__any(bv > tmin)) {            // wave-uniform branch
        if (bv > tmin) {                 // per-lane insert
          int col = cb + bj;
          #pragma unroll
          for (int q2 = 0; q2 < 8; ++q2)
            if (q2 == tmpos) { tv[q2] = bv; ti[q2] = col; }
          tmin = tv[0]; tmpos = 0;
          #pragma unroll
          for (int q2 = 1; q2 < 8; ++q2)
            if (tv[q2] < tmin) { tmin = tv[q2]; tmpos = q2; }
          #pragma unroll
          for (int j = 0; j < 8; ++j)
            if (j == bj) acc[j] = -INFINITY;
        }
        bv = acc[0]; bj = 0;
        #pragma unroll
        for (int j = 1; j < 8; ++j)
          if (acc[j] > bv) { bv = acc[j]; bj = j; }
      }
    }
    if (__any(bv > tmin)) {              // rare fallback (>=3 qualifiers)
      #pragma unroll
      for (int j = 0; j < 8; ++j) {
        float v = acc[j];
        if (v > tmin) {
          int col = cb + j;
          #pragma unroll
          for (int q2 = 0; q2 < 8; ++q2)
            if (q2 == tmpos) { tv[q2] = v; ti[q2] = col; }
          tmin = tv[0]; tmpos = 0;
          #pragma unroll
          for (int q2 = 1; q2 < 8; ++q2)
            if (tv[q2] < tmin) { tmin = tv[q2]; tmpos = q2; }
        }
      }
    }
  };

  // 3) seed with the first 8-col group
  {
    float a0[8], a1[8];
    compute8(stripe, a0, a1);
    #pragma unroll
    for (int j = 0; j < 8; ++j) {
      tv0[j] = a0[j]; ti0[j] = stripe + j;
      tv1[j] = a1[j]; ti1[j] = stripe + j;
    }
    tmin0 = tv0[0]; tmpos0 = 0; tmin1 = tv1[0]; tmpos1 = 0;
    #pragma unroll
    for (int q2 = 1; q2 < 8; ++q2) {
      if (tv0[q2] < tmin0) { tmin0 = tv0[q2]; tmpos0 = q2; }
      if (tv1[q2] < tmin1) { tmin1 = tv1[q2]; tmpos1 = q2; }
    }
  }

  // 4) remaining 15 groups
  #pragma unroll 1
  for (int cg = 1; cg < 16; ++cg) {
    const int cb = stripe + cg * 8;
    float a0[8], a1[8];
    compute8(cb, a0, a1);
    update8(cb, a0, tv0, ti0, tmin0, tmpos0);
    update8(cb, a1, tv1, ti1, tmin1, tmpos1);
  }

  // 5) block merge: 4 waves x 8 candidates -> chunk-local top-8 per row
  __syncthreads();                 // all qs reads done before aliasing cv/ci
  #pragma unroll
  for (int q2 = 0; q2 < 8; ++q2) {
    cv[lane][wu * 8 + q2] = tv0[q2];       ci[lane][wu * 8 + q2] = ti0[q2];
    cv[lane + 64][wu * 8 + q2] = tv1[q2];  ci[lane + 64][wu * 8 + q2] = ti1[q2];
  }
  __syncthreads();
  if (t < 128) {
    float rv[8]; int rid[8];
    #pragma unroll
    for (int q2 = 0; q2 < 8; ++q2) { rv[q2] = cv[t][q2]; rid[q2] = ci[t][q2]; }
    float m = rv[0]; int mp = 0;
    #pragma unroll
    for (int q2 = 1; q2 < 8; ++q2) if (rv[q2] < m) { m = rv[q2]; mp = q2; }
    #pragma unroll
    for (int c = 8; c < 32; ++c) {
      float v = cv[t][c];
      if (v > m) {
        int col = ci[t][c];
        #pragma unroll
        for (int q2 = 0; q2 < 8; ++q2) if (q2 == mp) { rv[q2] = v; rid[q2] = col; }
        m = rv[0]; mp = 0;
        #pragma unroll
        for (int q2 = 1; q2 < 8; ++q2) if (rv[q2] < m) { m = rv[q2]; mp = q2; }
      }
    }
    size_t gr = (size_t)(b * 4096 + n0) + t;
    #pragma unroll
    for (int q2 = 0; q2 < 8; ++q2) {
      wsv[gr * 64 + chunk * 8 + q2] = rv[q2];
      wsi[gr * 64 + chunk * 8 + q2] = rid[q2];
    }
  }
}

// ---------------- Kernel 3: merge 8 chunks (64 cand), softmax, scatter ------
__global__ __launch_bounds__(256) void merge_scatter(
    const float* __restrict__ wsv, const int* __restrict__ wsi,
    float* __restrict__ out) {
  int row = blockIdx.x * 256 + threadIdx.x;  // 0..16383
  const float4* v4 = (const float4*)(wsv + (size_t)row * 64);
  const int4*   i4 = (const int4*)(wsi + (size_t)row * 64);
  float rv[8]; int rid[8];
  {  // seed from first 8 candidates
    float4 a0 = v4[0], a1 = v4[1];
    int4   c0 = i4[0], c1 = i4[1];
    rv[0]=a0.x; rv[1]=a0.y; rv[2]=a0.z; rv[3]=a0.w;
    rv[4]=a1.x; rv[5]=a1.y; rv[6]=a1.z; rv[7]=a1.w;
    rid[0]=c0.x; rid[1]=c0.y; rid[2]=c0.z; rid[3]=c0.w;
    rid[4]=c1.x; rid[5]=c1.y; rid[6]=c1.z; rid[7]=c1.w;
  }
  float m = rv[0]; int mp = 0;
  #pragma unroll
  for (int q = 1; q < 8; ++q) if (rv[q] < m) { m = rv[q]; mp = q; }
  #pragma unroll 2
  for (int c4 = 2; c4 < 16; ++c4) {
    float4 a = v4[c4]; int4 ic = i4[c4];
    const float vv[4] = {a.x, a.y, a.z, a.w};
    const int   ii[4] = {ic.x, ic.y, ic.z, ic.w};
    #pragma unroll
    for (int k = 0; k < 4; ++k) {
      if (vv[k] > m) {
        #pragma unroll
        for (int q = 0; q < 8; ++q) if (q == mp) { rv[q] = vv[k]; rid[q] = ii[k]; }
        m = rv[0]; mp = 0;
        #pragma unroll
        for (int q = 1; q < 8; ++q) if (rv[q] < m) { m = rv[q]; mp = q; }
      }
    }
  }
  float vmax = rv[0];
  #pragma unroll
  for (int q = 1; q < 8; ++q) vmax = fmaxf(vmax, rv[q]);
  float e[8], s = 0.f;
  #pragma unroll
  for (int q = 0; q < 8; ++q) { e[q] = __expf((rv[q] - vmax) * SCALE); s += e[q]; }
  float inv = 1.f / s;
  float* orow = out + (size_t)row * NCOL;
  #pragma unroll
  for (int q = 0; q < 8; ++q) orow[rid[q]] = e[q] * inv;
}

extern "C" void kernel_launch(void* const* d_in, const int* in_sizes, int n_in,
                              void* d_out, int out_size, void* d_ws, size_t ws_size,
                              hipStream_t stream) {
  const float* x  = (const float*)d_in[0];
  const float* Wq = (const float*)d_in[1];
  const float* Wk = (const float*)d_in[2];
  float* out = (float*)d_out;

  char* ws = (char*)d_ws;
  float* Qt  = (float*)ws;                                   // 4 MB
  float* Kt  = (float*)(ws + (size_t)NROW * DKDIM * 4);      // 4 MB
  float* wsv = (float*)(ws + 2 * (size_t)NROW * DKDIM * 4);  // 4 MB
  int*   wsi = (int*)  (ws + 2 * (size_t)NROW * DKDIM * 4 + (size_t)NROW * 64 * 4); // 4 MB

  qk_proj<<<dim3(NROW / 64), 512, 0, stream>>>(x, Wq, Wk, Qt, Kt);
  s_topk<<<1024, 256, 0, stream>>>(Qt, Kt, out, wsv, wsi);
  merge_scatter<<<NROW / 256, 256, 0, stream>>>(wsv, wsi, out);
}